// Round 4
// baseline (922.701 us; speedup 1.0000x reference)
//
#include <hip/hip_runtime.h>
#include <cstdint>
#include <cstddef>

#define B_  2
#define S_  2048
#define H_  768
#define NH  12
#define DH  64
#define RD  5
#define BN  (B_*NH)   // 24

typedef _Float16 f16;
typedef __attribute__((ext_vector_type(8))) _Float16 f16x8;
typedef __attribute__((ext_vector_type(4))) float f32x4;

#define MFMA16(a, b, c) __builtin_amdgcn_mfma_f32_16x16x32_f16((a), (b), (c), 0, 0, 0)

#if __has_builtin(__builtin_amdgcn_exp2f)
__device__ __forceinline__ float exp2fast(float x) { return __builtin_amdgcn_exp2f(x); }
#else
__device__ __forceinline__ float exp2fast(float x) { return __expf(0.69314718056f * x); }
#endif

#define SCL 0.1803368801f   /* 0.125 * log2(e) */
#define L2E 1.44269504f

#define NX4 ((B_*S_*H_)/4)   // 786432
#define NW4 ((H_*H_)/4)      // 147456

// ---------------------------------------------------------------------------
// Kernel 0: fused fp32 -> fp16 conversion of x, Wq, Wk, Wv (one launch).
// ---------------------------------------------------------------------------
__global__ __launch_bounds__(256) void cvtall(
    const float* __restrict__ x,
    const float* __restrict__ wq, const float* __restrict__ wk,
    const float* __restrict__ wv,
    f16* __restrict__ xh, f16* __restrict__ wh)
{
    int idx = blockIdx.x * 256 + threadIdx.x;
    const int total4 = NX4 + 3 * NW4;
    if (idx >= total4) return;
    const float* src;
    f16* dst;
    int off;
    if (idx < NX4) {
        src = x; dst = xh; off = idx;
    } else {
        int r = idx - NX4;
        int which = r / NW4;
        off = r - which * NW4;
        src = (which == 0) ? wq : (which == 1) ? wk : wv;
        dst = wh + (size_t)which * H_ * H_;
    }
    float4 f = ((const float4*)src)[off];
    f16 h[4] = {(f16)f.x, (f16)f.y, (f16)f.z, (f16)f.w};
    ((ushort4*)dst)[off] = *(const ushort4*)h;
}

// ---------------------------------------------------------------------------
// Kernel 1: MFMA QKV projection (fp16 in/out).  One block: 64 rows x 64 cols
// of q,k,v (same x tile, three W tiles).  V written transposed vt[bn][d][s].
// grid (12, 64).
// ---------------------------------------------------------------------------
__global__ __launch_bounds__(256, 3) void qkv_gemm(
    const f16* __restrict__ xh, const f16* __restrict__ wh,
    const float* __restrict__ bq, const float* __restrict__ bk,
    const float* __restrict__ bv,
    f16* __restrict__ qo, f16* __restrict__ ko, f16* __restrict__ vt)
{
    __shared__ __align__(16) f16 Xs[64][72];
    __shared__ __align__(16) f16 Ws[3][64][72];

    const int tid = threadIdx.x;
    const int n  = blockIdx.x;          // head / 64-col tile
    const int m0 = blockIdx.y * 64;
    const int w = tid >> 6, lane = tid & 63;
    const int l15 = lane & 15, quad = lane >> 4;
    const int srow = tid >> 2, sc0 = (tid & 3) * 16;

    f32x4 acc[3][4];
#pragma unroll
    for (int i = 0; i < 3; ++i)
#pragma unroll
        for (int ns = 0; ns < 4; ++ns) acc[i][ns] = (f32x4){0.f, 0.f, 0.f, 0.f};

    const f16* xsrc = xh + (size_t)(m0 + srow) * H_ + sc0;
    const f16* wsrc = wh + (size_t)(n * 64 + srow) * H_ + sc0;

    for (int kc = 0; kc < 12; ++kc) {
        __syncthreads();
        {
            const f16* s0 = xsrc + kc * 64;
            *(f16x8*)&Xs[srow][sc0]     = *(const f16x8*)(s0);
            *(f16x8*)&Xs[srow][sc0 + 8] = *(const f16x8*)(s0 + 8);
        }
#pragma unroll
        for (int i = 0; i < 3; ++i) {
            const f16* s0 = wsrc + (size_t)i * H_ * H_ + kc * 64;
            *(f16x8*)&Ws[i][srow][sc0]     = *(const f16x8*)(s0);
            *(f16x8*)&Ws[i][srow][sc0 + 8] = *(const f16x8*)(s0 + 8);
        }
        __syncthreads();

        f16x8 a0 = *(const f16x8*)&Xs[w * 16 + l15][quad * 8];
        f16x8 a1 = *(const f16x8*)&Xs[w * 16 + l15][quad * 8 + 32];
#pragma unroll
        for (int i = 0; i < 3; ++i)
#pragma unroll
            for (int ns = 0; ns < 4; ++ns) {
                f16x8 b0 = *(const f16x8*)&Ws[i][ns * 16 + l15][quad * 8];
                f16x8 b1 = *(const f16x8*)&Ws[i][ns * 16 + l15][quad * 8 + 32];
                acc[i][ns] = MFMA16(a0, b0, acc[i][ns]);
                acc[i][ns] = MFMA16(a1, b1, acc[i][ns]);
            }
    }
    __syncthreads();

    const float* bias[3] = {bq, bk, bv};
    f16 (*T0)[72] = Xs;      // q
    f16 (*T1)[72] = Ws[0];   // k
    f16 (*T2)[72] = Ws[1];   // v
#pragma unroll
    for (int i = 0; i < 3; ++i) {
        f16 (*T)[72] = (i == 0) ? T0 : (i == 1) ? T1 : T2;
#pragma unroll
        for (int ns = 0; ns < 4; ++ns) {
            float bb = bias[i][n * 64 + ns * 16 + l15];
#pragma unroll
            for (int reg = 0; reg < 4; ++reg)
                T[w * 16 + quad * 4 + reg][ns * 16 + l15] =
                    (f16)(acc[i][ns][reg] + bb);
        }
    }
    __syncthreads();

    const int mrow = m0 + srow;
    const int bb2 = mrow >> 11, ss = mrow & 2047;
    {
        f16* dst = qo + ((size_t)(bb2 * NH + n) * S_ + ss) * DH + sc0;
        *(f16x8*)dst       = *(const f16x8*)&T0[srow][sc0];
        *(f16x8*)(dst + 8) = *(const f16x8*)&T0[srow][sc0 + 8];
    }
    {
        f16* dst = ko + ((size_t)(bb2 * NH + n) * S_ + ss) * DH + sc0;
        *(f16x8*)dst       = *(const f16x8*)&T1[srow][sc0];
        *(f16x8*)(dst + 8) = *(const f16x8*)&T1[srow][sc0 + 8];
    }
    {
        f16 tmp[16];
#pragma unroll
        for (int u = 0; u < 16; ++u) tmp[u] = T2[sc0 + u][srow];
        f16* dst = vt + ((size_t)(bb2 * NH + n) * DH + srow) * S_ + (m0 & 2047) + sc0;
        *(f16x8*)dst       = *(const f16x8*)&tmp[0];
        *(f16x8*)(dst + 8) = *(const f16x8*)&tmp[8];
    }
}

// ---------------------------------------------------------------------------
// Kernel 2: pack binary adjacency -> bytes, i-quad interleaved, VECTORIZED.
// ---------------------------------------------------------------------------
__global__ __launch_bounds__(256) void adjpack(
    const float* __restrict__ adj, unsigned char* __restrict__ adjp)
{
    const int idx4 = blockIdx.x * 256 + threadIdx.x;   // [0, 2^19)
    const int j4 = idx4 & 511;          // j = j4*4
    const int iq = (idx4 >> 9) & 511;
    const int b  = idx4 >> 18;
    unsigned int wbits[4] = {0, 0, 0, 0};   // per-j packed (ii in byte lanes)
#pragma unroll
    for (int r = 0; r < RD; ++r) {
#pragma unroll
        for (int ii = 0; ii < 4; ++ii) {
            float4 v = *(const float4*)(adj +
                (((size_t)(r * B_ + b) * S_) + iq * 4 + ii) * S_ + j4 * 4);
            float vv[4] = {v.x, v.y, v.z, v.w};
#pragma unroll
            for (int jj = 0; jj < 4; ++jj)
                wbits[jj] |= (vv[jj] != 0.f ? 1u : 0u) << (r + 8 * ii);
        }
    }
    uint4 pk = {wbits[0], wbits[1], wbits[2], wbits[3]};
    *(uint4*)(adjp + ((size_t)(b * 512 + iq) * S_ + j4 * 4) * 4) = pk;
}

// ---------------------------------------------------------------------------
// Kernel 3: MFMA flash attention with TWO-TILE SOFTWARE PIPELINE.
// Occupancy is GRID-PINNED at 3 waves/SIMD (3072 waves total / 1024 SIMDs);
// rounds 1-3 proved neither launch bounds nor block-splitting raise it
// without register blowup.  So this round attacks per-wave ILP instead:
// scores(t+1) (48 MFMAs, independent of softmax state) is computed ahead
// and interleaved with softmax+PV(t) via two statically-named score
// buffers scA/scB (rule #20: no runtime-indexed selection).  Launch bounds
// relaxed to (256,3): budget ~170 regs, occupancy can't exceed 3 anyway.
// ---------------------------------------------------------------------------
__global__ __launch_bounds__(256, 3) void attn(
    const f16* __restrict__ q, const f16* __restrict__ k, const f16* __restrict__ vt,
    const float* __restrict__ bili, const unsigned char* __restrict__ adjp,
    const float* __restrict__ mask, const float* __restrict__ absb,
    float* __restrict__ out)
{
    __shared__ __align__(16) char smem[9216 + 9216 + 128];
    f16*   Mt  = (f16*)smem;                    // [64][72] (prologue only)
    f16*   Pb  = (f16*)(smem + 9216);           // [4][16][72]
    float* lut = (float*)(smem + 9216 + 9216);  // [32]

    const int tid = threadIdx.x;
    const int idx = blockIdx.x;
    const int g = idx & 7;
    const int it = (idx >> 3) & 31;
    const int bn = 8 * (idx >> 8) + g;
    const int b = bn / NH, n = bn % NH;
    const int w = tid >> 6, lane = tid & 63;
    const int l15 = lane & 15, quad = lane >> 4;
    const int wi0 = it * 64 + w * 16;
    const size_t kbase = (size_t)bn * S_ * DH;

    if (tid < 32) {
        float a = 0.f;
#pragma unroll
        for (int r = 0; r < RD; ++r)
            if (tid & (1 << r)) a += absb[r * NH + n];
        lut[tid] = a * SCL;
    }

    const f16* qrow = q + kbase + (size_t)(wi0 + l15) * DH + quad * 8;
    f16x8 aq0 = *(const f16x8*)(qrow);
    f16x8 aq1 = *(const f16x8*)(qrow + 32);

    f16* Pw = Pb + w * 16 * 72;

    // ---- build Q'_r A-frags via MFMA (M_r staged transposed in LDS) ----
    f16x8 aqp[RD][2];
#pragma unroll
    for (int r = 0; r < RD; ++r) {
        __syncthreads();
        {
            int p = tid >> 2, q0 = (tid & 3) * 16;
            const float* src = bili + ((size_t)(r * NH + n) * DH + p) * DH + q0;
            float4 g0 = ((const float4*)src)[0];
            float4 g1 = ((const float4*)src)[1];
            float4 g2 = ((const float4*)src)[2];
            float4 g3 = ((const float4*)src)[3];
            float mv[16] = {g0.x, g0.y, g0.z, g0.w, g1.x, g1.y, g1.z, g1.w,
                            g2.x, g2.y, g2.z, g2.w, g3.x, g3.y, g3.z, g3.w};
#pragma unroll
            for (int u = 0; u < 16; ++u) Mt[(q0 + u) * 72 + p] = (f16)mv[u];
        }
        __syncthreads();
#pragma unroll
        for (int ns = 0; ns < 4; ++ns) {
            f16x8 b0 = *(const f16x8*)&Mt[(ns * 16 + l15) * 72 + quad * 8];
            f16x8 b1 = *(const f16x8*)&Mt[(ns * 16 + l15) * 72 + quad * 8 + 32];
            f32x4 d = {0.f, 0.f, 0.f, 0.f};
            d = MFMA16(aq0, b0, d);
            d = MFMA16(aq1, b1, d);
#pragma unroll
            for (int reg = 0; reg < 4; ++reg)
                Pw[(quad * 4 + reg) * 72 + ns * 16 + l15] = (f16)d[reg];
        }
        aqp[r][0] = *(const f16x8*)&Pw[l15 * 72 + quad * 8];
        aqp[r][1] = *(const f16x8*)&Pw[l15 * 72 + quad * 8 + 32];
    }

    f16x8 ones;
#pragma unroll
    for (int u = 0; u < 8; ++u) ones[u] = (f16)1.0f;

    f32x4 o[4] = {{0,0,0,0},{0,0,0,0},{0,0,0,0},{0,0,0,0}};
    f32x4 lacc = {0.f, 0.f, 0.f, 0.f};
    float mrun[4] = {-1e30f, -1e30f, -1e30f, -1e30f};

    const unsigned char* adjrow =
        adjp + (size_t)(b * 512 + (wi0 >> 2) + quad) * (S_ * 4);
    const float* maskrow = mask + (size_t)b * S_;
    const f16* vtb = vt + (size_t)bn * DH * S_;

// SCORES(T, SC): 48 MFMAs + VALU fixup -> SC[4][4].  Independent of
// softmax state (mrun/o/lacc) -> freely schedulable against SMPV.
#define SCORES(T, SC) do {                                                   \
    const int j0_ = (T) * 64;                                                \
    _Pragma("unroll")                                                        \
    for (int js = 0; js < 4; ++js) {                                         \
        const int jcol = j0_ + js * 16 + l15;                                \
        const f16* kp = k + kbase + (size_t)jcol * DH + quad * 8;            \
        f16x8 bk0 = *(const f16x8*)(kp);                                     \
        f16x8 bk1 = *(const f16x8*)(kp + 32);                                \
        f32x4 aqk = {0.f, 0.f, 0.f, 0.f};                                    \
        aqk = MFMA16(aq0, bk0, aqk);                                         \
        aqk = MFMA16(aq1, bk1, aqk);                                         \
        uchar4 a4 = *(const uchar4*)(adjrow + (size_t)jcol * 4);             \
        unsigned int c0 = a4.x, c1 = a4.y, c2 = a4.z, c3 = a4.w;             \
        float mkL = maskrow[jcol] * L2E;                                     \
        float s0 = aqk[0], s1 = aqk[1], s2 = aqk[2], s3 = aqk[3];            \
        _Pragma("unroll")                                                    \
        for (int r = 0; r < RD; ++r) {                                       \
            f32x4 z = {0.f, 0.f, 0.f, 0.f};                                  \
            z = MFMA16(aqp[r][0], bk0, z);                                   \
            z = MFMA16(aqp[r][1], bk1, z);                                   \
            s0 = fmaf((float)((c0 >> r) & 1u), z[0], s0);                    \
            s1 = fmaf((float)((c1 >> r) & 1u), z[1], s1);                    \
            s2 = fmaf((float)((c2 >> r) & 1u), z[2], s2);                    \
            s3 = fmaf((float)((c3 >> r) & 1u), z[3], s3);                    \
        }                                                                    \
        SC[js][0] = fmaf(s0, SCL, lut[c0] + mkL);                            \
        SC[js][1] = fmaf(s1, SCL, lut[c1] + mkL);                            \
        SC[js][2] = fmaf(s2, SCL, lut[c2] + mkL);                            \
        SC[js][3] = fmaf(s3, SCL, lut[c3] + mkL);                            \
    }                                                                        \
} while (0)

// SMPV(T, SC): online softmax + P pack + rescale + PV for tile T.
#define SMPV(T, SC) do {                                                     \
    const int j0_ = (T) * 64;                                                \
    float alpha[4];                                                          \
    _Pragma("unroll")                                                        \
    for (int reg = 0; reg < 4; ++reg) {                                      \
        float nm = fmaxf(fmaxf(SC[0][reg], SC[1][reg]),                      \
                         fmaxf(SC[2][reg], SC[3][reg]));                     \
        _Pragma("unroll")                                                    \
        for (int off = 1; off < 16; off <<= 1)                               \
            nm = fmaxf(nm, __shfl_xor(nm, off));                             \
        float mn = fmaxf(mrun[reg], nm);                                     \
        alpha[reg] = exp2fast(mrun[reg] - mn);                               \
        mrun[reg] = mn;                                                      \
    }                                                                        \
    _Pragma("unroll")                                                        \
    for (int js = 0; js < 4; ++js)                                           \
        _Pragma("unroll")                                                    \
        for (int reg = 0; reg < 4; ++reg) {                                  \
            float p = exp2fast(SC[js][reg] - mrun[reg]);                     \
            Pw[(quad * 4 + reg) * 72 + js * 16 + l15] = (f16)p;              \
        }                                                                    \
    _Pragma("unroll")                                                        \
    for (int reg = 0; reg < 4; ++reg) {                                      \
        lacc[reg] *= alpha[reg];                                             \
        _Pragma("unroll")                                                    \
        for (int ds = 0; ds < 4; ++ds) o[ds][reg] *= alpha[reg];             \
    }                                                                        \
    f16x8 pa0 = *(const f16x8*)&Pw[l15 * 72 + quad * 8];                     \
    f16x8 pa1 = *(const f16x8*)&Pw[l15 * 72 + quad * 8 + 32];                 \
    lacc = MFMA16(pa0, ones, lacc);                                          \
    lacc = MFMA16(pa1, ones, lacc);                                          \
    _Pragma("unroll")                                                        \
    for (int ds = 0; ds < 4; ++ds) {                                         \
        const f16* vp = vtb + (size_t)(ds * 16 + l15) * S_ + j0_ + quad * 8; \
        f16x8 bv0 = *(const f16x8*)(vp);                                     \
        f16x8 bv1 = *(const f16x8*)(vp + 32);                                \
        o[ds] = MFMA16(pa0, bv0, o[ds]);                                     \
        o[ds] = MFMA16(pa1, bv1, o[ds]);                                     \
    }                                                                        \
} while (0)

    float scA[4][4], scB[4][4];
    SCORES(0, scA);
#pragma unroll 1
    for (int tt = 0; tt < 16; ++tt) {
        SCORES(2 * tt + 1, scB);      // independent of SMPV below -> overlap
        SMPV(2 * tt, scA);
        if (tt < 15) SCORES(2 * tt + 2, scA);
        SMPV(2 * tt + 1, scB);
    }

#undef SCORES
#undef SMPV

    // ---- epilogue ----
#pragma unroll
    for (int reg = 0; reg < 4; ++reg) {
        float inv = 1.f / lacc[reg];
        int i = wi0 + quad * 4 + reg;
#pragma unroll
        for (int ds = 0; ds < 4; ++ds)
            out[((size_t)b * S_ + i) * H_ + n * DH + ds * 16 + l15] =
                o[ds][reg] * inv;
    }
}

// ---------------------------------------------------------------------------
extern "C" void kernel_launch(void* const* d_in, const int* in_sizes, int n_in,
                              void* d_out, int out_size, void* d_ws, size_t ws_size,
                              hipStream_t stream)
{
    const float* hs   = (const float*)d_in[0];
    const float* mask = (const float*)d_in[1];
    const float* adj  = (const float*)d_in[2];
    const float* Wq   = (const float*)d_in[3];
    const float* bq   = (const float*)d_in[4];
    const float* Wk   = (const float*)d_in[5];
    const float* bk   = (const float*)d_in[6];
    const float* Wv   = (const float*)d_in[7];
    const float* bv   = (const float*)d_in[8];
    const float* bili = (const float*)d_in[9];
    const float* absb = (const float*)d_in[10];
    float* out = (float*)d_out;

    const size_t QKV = (size_t)BN * S_ * DH;       // 3.1M elems
    f16* q  = (f16*)d_ws;
    f16* k  = q + QKV;
    f16* vt = k + QKV;
    unsigned char* adjp = (unsigned char*)(vt + QKV);       // 8 MB
    f16* xh = (f16*)(adjp + (size_t)B_ * 512 * S_ * 4);
    f16* wh = xh + (size_t)B_ * S_ * H_;                    // Wq|Wk|Wv f16

    const int total4 = NX4 + 3 * NW4;
    cvtall<<<(total4 + 255) / 256, 256, 0, stream>>>(hs, Wq, Wk, Wv, xh, wh);
    qkv_gemm<<<dim3(12, 64), 256, 0, stream>>>(xh, wh, bq, bk, bv, q, k, vt);
    adjpack<<<2048, 256, 0, stream>>>(adj, adjp);
    attn<<<768, 256, 0, stream>>>(q, k, vt, bili, adjp, mask, absb, out);
}

// Round 5
// 919.768 us; speedup vs baseline: 1.0032x; 1.0032x over previous
//
#include <hip/hip_runtime.h>
#include <cstdint>
#include <cstddef>

#define B_  2
#define S_  2048
#define H_  768
#define NH  12
#define DH  64
#define RD  5
#define BN  (B_*NH)   // 24

typedef _Float16 f16;
typedef __attribute__((ext_vector_type(8))) _Float16 f16x8;
typedef __attribute__((ext_vector_type(4))) float f32x4;

#define MFMA16(a, b, c) __builtin_amdgcn_mfma_f32_16x16x32_f16((a), (b), (c), 0, 0, 0)

#if __has_builtin(__builtin_amdgcn_exp2f)
__device__ __forceinline__ float exp2fast(float x) { return __builtin_amdgcn_exp2f(x); }
#else
__device__ __forceinline__ float exp2fast(float x) { return __expf(0.69314718056f * x); }
#endif

#define SCL 0.1803368801f   /* 0.125 * log2(e) */
#define L2E 1.44269504f

#define NX4 ((B_*S_*H_)/4)   // 786432
#define NW4 ((H_*H_)/4)      // 147456

// ---------------------------------------------------------------------------
// Kernel 0: fused fp32 -> fp16 conversion of x, Wq, Wk, Wv (one launch).
// ---------------------------------------------------------------------------
__global__ __launch_bounds__(256) void cvtall(
    const float* __restrict__ x,
    const float* __restrict__ wq, const float* __restrict__ wk,
    const float* __restrict__ wv,
    f16* __restrict__ xh, f16* __restrict__ wh)
{
    int idx = blockIdx.x * 256 + threadIdx.x;
    const int total4 = NX4 + 3 * NW4;
    if (idx >= total4) return;
    const float* src;
    f16* dst;
    int off;
    if (idx < NX4) {
        src = x; dst = xh; off = idx;
    } else {
        int r = idx - NX4;
        int which = r / NW4;
        off = r - which * NW4;
        src = (which == 0) ? wq : (which == 1) ? wk : wv;
        dst = wh + (size_t)which * H_ * H_;
    }
    float4 f = ((const float4*)src)[off];
    f16 h[4] = {(f16)f.x, (f16)f.y, (f16)f.z, (f16)f.w};
    ((ushort4*)dst)[off] = *(const ushort4*)h;
}

// ---------------------------------------------------------------------------
// Kernel 1: MFMA QKV projection (fp16 in/out).  One block: 64 rows x 64 cols
// of q,k,v (same x tile, three W tiles).  V written transposed vt[bn][d][s].
// grid (12, 64).
// ---------------------------------------------------------------------------
__global__ __launch_bounds__(256, 3) void qkv_gemm(
    const f16* __restrict__ xh, const f16* __restrict__ wh,
    const float* __restrict__ bq, const float* __restrict__ bk,
    const float* __restrict__ bv,
    f16* __restrict__ qo, f16* __restrict__ ko, f16* __restrict__ vt)
{
    __shared__ __align__(16) f16 Xs[64][72];
    __shared__ __align__(16) f16 Ws[3][64][72];

    const int tid = threadIdx.x;
    const int n  = blockIdx.x;          // head / 64-col tile
    const int m0 = blockIdx.y * 64;
    const int w = tid >> 6, lane = tid & 63;
    const int l15 = lane & 15, quad = lane >> 4;
    const int srow = tid >> 2, sc0 = (tid & 3) * 16;

    f32x4 acc[3][4];
#pragma unroll
    for (int i = 0; i < 3; ++i)
#pragma unroll
        for (int ns = 0; ns < 4; ++ns) acc[i][ns] = (f32x4){0.f, 0.f, 0.f, 0.f};

    const f16* xsrc = xh + (size_t)(m0 + srow) * H_ + sc0;
    const f16* wsrc = wh + (size_t)(n * 64 + srow) * H_ + sc0;

    for (int kc = 0; kc < 12; ++kc) {
        __syncthreads();
        {
            const f16* s0 = xsrc + kc * 64;
            *(f16x8*)&Xs[srow][sc0]     = *(const f16x8*)(s0);
            *(f16x8*)&Xs[srow][sc0 + 8] = *(const f16x8*)(s0 + 8);
        }
#pragma unroll
        for (int i = 0; i < 3; ++i) {
            const f16* s0 = wsrc + (size_t)i * H_ * H_ + kc * 64;
            *(f16x8*)&Ws[i][srow][sc0]     = *(const f16x8*)(s0);
            *(f16x8*)&Ws[i][srow][sc0 + 8] = *(const f16x8*)(s0 + 8);
        }
        __syncthreads();

        f16x8 a0 = *(const f16x8*)&Xs[w * 16 + l15][quad * 8];
        f16x8 a1 = *(const f16x8*)&Xs[w * 16 + l15][quad * 8 + 32];
#pragma unroll
        for (int i = 0; i < 3; ++i)
#pragma unroll
            for (int ns = 0; ns < 4; ++ns) {
                f16x8 b0 = *(const f16x8*)&Ws[i][ns * 16 + l15][quad * 8];
                f16x8 b1 = *(const f16x8*)&Ws[i][ns * 16 + l15][quad * 8 + 32];
                acc[i][ns] = MFMA16(a0, b0, acc[i][ns]);
                acc[i][ns] = MFMA16(a1, b1, acc[i][ns]);
            }
    }
    __syncthreads();

    const float* bias[3] = {bq, bk, bv};
    f16 (*T0)[72] = Xs;      // q
    f16 (*T1)[72] = Ws[0];   // k
    f16 (*T2)[72] = Ws[1];   // v
#pragma unroll
    for (int i = 0; i < 3; ++i) {
        f16 (*T)[72] = (i == 0) ? T0 : (i == 1) ? T1 : T2;
#pragma unroll
        for (int ns = 0; ns < 4; ++ns) {
            float bb = bias[i][n * 64 + ns * 16 + l15];
#pragma unroll
            for (int reg = 0; reg < 4; ++reg)
                T[w * 16 + quad * 4 + reg][ns * 16 + l15] =
                    (f16)(acc[i][ns][reg] + bb);
        }
    }
    __syncthreads();

    const int mrow = m0 + srow;
    const int bb2 = mrow >> 11, ss = mrow & 2047;
    {
        f16* dst = qo + ((size_t)(bb2 * NH + n) * S_ + ss) * DH + sc0;
        *(f16x8*)dst       = *(const f16x8*)&T0[srow][sc0];
        *(f16x8*)(dst + 8) = *(const f16x8*)&T0[srow][sc0 + 8];
    }
    {
        f16* dst = ko + ((size_t)(bb2 * NH + n) * S_ + ss) * DH + sc0;
        *(f16x8*)dst       = *(const f16x8*)&T1[srow][sc0];
        *(f16x8*)(dst + 8) = *(const f16x8*)&T1[srow][sc0 + 8];
    }
    {
        f16 tmp[16];
#pragma unroll
        for (int u = 0; u < 16; ++u) tmp[u] = T2[sc0 + u][srow];
        f16* dst = vt + ((size_t)(bb2 * NH + n) * DH + srow) * S_ + (m0 & 2047) + sc0;
        *(f16x8*)dst       = *(const f16x8*)&tmp[0];
        *(f16x8*)(dst + 8) = *(const f16x8*)&tmp[8];
    }
}

// ---------------------------------------------------------------------------
// Kernel 2: pack binary adjacency -> bytes, i-quad interleaved, VECTORIZED.
// ---------------------------------------------------------------------------
__global__ __launch_bounds__(256) void adjpack(
    const float* __restrict__ adj, unsigned char* __restrict__ adjp)
{
    const int idx4 = blockIdx.x * 256 + threadIdx.x;   // [0, 2^19)
    const int j4 = idx4 & 511;          // j = j4*4
    const int iq = (idx4 >> 9) & 511;
    const int b  = idx4 >> 18;
    unsigned int wbits[4] = {0, 0, 0, 0};   // per-j packed (ii in byte lanes)
#pragma unroll
    for (int r = 0; r < RD; ++r) {
#pragma unroll
        for (int ii = 0; ii < 4; ++ii) {
            float4 v = *(const float4*)(adj +
                (((size_t)(r * B_ + b) * S_) + iq * 4 + ii) * S_ + j4 * 4);
            float vv[4] = {v.x, v.y, v.z, v.w};
#pragma unroll
            for (int jj = 0; jj < 4; ++jj)
                wbits[jj] |= (vv[jj] != 0.f ? 1u : 0u) << (r + 8 * ii);
        }
    }
    uint4 pk = {wbits[0], wbits[1], wbits[2], wbits[3]};
    *(uint4*)(adjp + ((size_t)(b * 512 + iq) * S_ + j4 * 4) * 4) = pk;
}

// ---------------------------------------------------------------------------
// Kernel 3: MFMA flash attention, TWO-TILE PIPELINE, ZERO-ARRAY edition.
// Round-4's pipeline put scA/scB in scratch (SROA failure on cross-macro,
// conditionally-written, loop-carried arrays: VGPR=84 + 2.3 GB hbm traffic).
// This version has NO arrays in loop state: 32 named score scalars
// (token-pasted), named qp0a..qp4b fragments (prologue manually unrolled),
// named o0..o3 / mr0..mr3.  Nothing addressable -> nothing demotable.
// Occupancy is grid-pinned at 3 waves/SIMD; the win sought here is per-wave
// ILP: SCORES(t+1) (48 indep MFMAs + K loads) interleaves with SMPV(t).
// ---------------------------------------------------------------------------
__global__ __launch_bounds__(256, 3) void attn(
    const f16* __restrict__ q, const f16* __restrict__ k, const f16* __restrict__ vt,
    const float* __restrict__ bili, const unsigned char* __restrict__ adjp,
    const float* __restrict__ mask, const float* __restrict__ absb,
    float* __restrict__ out)
{
    __shared__ __align__(16) char smem[9216 + 9216 + 128];
    f16*   Mt  = (f16*)smem;                    // [64][72] (prologue only)
    f16*   Pb  = (f16*)(smem + 9216);           // [4][16][72]
    float* lut = (float*)(smem + 9216 + 9216);  // [32]

    const int tid = threadIdx.x;
    const int idx = blockIdx.x;
    const int g = idx & 7;
    const int it = (idx >> 3) & 31;
    const int bn = 8 * (idx >> 8) + g;
    const int b = bn / NH, n = bn % NH;
    const int w = tid >> 6, lane = tid & 63;
    const int l15 = lane & 15, quad = lane >> 4;
    const int wi0 = it * 64 + w * 16;
    const size_t kbase = (size_t)bn * S_ * DH;

    if (tid < 32) {
        float a = 0.f;
#pragma unroll
        for (int r = 0; r < RD; ++r)
            if (tid & (1 << r)) a += absb[r * NH + n];
        lut[tid] = a * SCL;
    }

    const f16* qrow = q + kbase + (size_t)(wi0 + l15) * DH + quad * 8;
    f16x8 aq0 = *(const f16x8*)(qrow);
    f16x8 aq1 = *(const f16x8*)(qrow + 32);

    f16* Pw = Pb + w * 16 * 72;

// ---- prologue: build Q'_r A-frags (manually unrolled, named outputs) ----
#define BUILD_QP(R, QPa, QPb) do {                                           \
    __syncthreads();                                                         \
    {                                                                        \
        int p_ = tid >> 2, q0_ = (tid & 3) * 16;                             \
        const float* src_ = bili + ((size_t)((R) * NH + n) * DH + p_) * DH + q0_; \
        float4 g0_ = ((const float4*)src_)[0];                               \
        float4 g1_ = ((const float4*)src_)[1];                               \
        float4 g2_ = ((const float4*)src_)[2];                               \
        float4 g3_ = ((const float4*)src_)[3];                               \
        Mt[(q0_ +  0) * 72 + p_] = (f16)g0_.x;                               \
        Mt[(q0_ +  1) * 72 + p_] = (f16)g0_.y;                               \
        Mt[(q0_ +  2) * 72 + p_] = (f16)g0_.z;                               \
        Mt[(q0_ +  3) * 72 + p_] = (f16)g0_.w;                               \
        Mt[(q0_ +  4) * 72 + p_] = (f16)g1_.x;                               \
        Mt[(q0_ +  5) * 72 + p_] = (f16)g1_.y;                               \
        Mt[(q0_ +  6) * 72 + p_] = (f16)g1_.z;                               \
        Mt[(q0_ +  7) * 72 + p_] = (f16)g1_.w;                               \
        Mt[(q0_ +  8) * 72 + p_] = (f16)g2_.x;                               \
        Mt[(q0_ +  9) * 72 + p_] = (f16)g2_.y;                               \
        Mt[(q0_ + 10) * 72 + p_] = (f16)g2_.z;                               \
        Mt[(q0_ + 11) * 72 + p_] = (f16)g2_.w;                               \
        Mt[(q0_ + 12) * 72 + p_] = (f16)g3_.x;                               \
        Mt[(q0_ + 13) * 72 + p_] = (f16)g3_.y;                               \
        Mt[(q0_ + 14) * 72 + p_] = (f16)g3_.z;                               \
        Mt[(q0_ + 15) * 72 + p_] = (f16)g3_.w;                               \
    }                                                                        \
    __syncthreads();                                                         \
    _Pragma("unroll")                                                        \
    for (int ns = 0; ns < 4; ++ns) {                                         \
        f16x8 b0_ = *(const f16x8*)&Mt[(ns * 16 + l15) * 72 + quad * 8];     \
        f16x8 b1_ = *(const f16x8*)&Mt[(ns * 16 + l15) * 72 + quad * 8 + 32];\
        f32x4 d_ = {0.f, 0.f, 0.f, 0.f};                                     \
        d_ = MFMA16(aq0, b0_, d_);                                           \
        d_ = MFMA16(aq1, b1_, d_);                                           \
        Pw[(quad * 4 + 0) * 72 + ns * 16 + l15] = (f16)d_[0];                \
        Pw[(quad * 4 + 1) * 72 + ns * 16 + l15] = (f16)d_[1];                \
        Pw[(quad * 4 + 2) * 72 + ns * 16 + l15] = (f16)d_[2];                \
        Pw[(quad * 4 + 3) * 72 + ns * 16 + l15] = (f16)d_[3];                \
    }                                                                        \
    QPa = *(const f16x8*)&Pw[l15 * 72 + quad * 8];                           \
    QPb = *(const f16x8*)&Pw[l15 * 72 + quad * 8 + 32];                      \
} while (0)

    f16x8 qp0a, qp0b, qp1a, qp1b, qp2a, qp2b, qp3a, qp3b, qp4a, qp4b;
    BUILD_QP(0, qp0a, qp0b);
    BUILD_QP(1, qp1a, qp1b);
    BUILD_QP(2, qp2a, qp2b);
    BUILD_QP(3, qp3a, qp3b);
    BUILD_QP(4, qp4a, qp4b);
#undef BUILD_QP

    f16x8 ones;
#pragma unroll
    for (int u = 0; u < 8; ++u) ones[u] = (f16)1.0f;

    f32x4 o0 = {0,0,0,0}, o1 = {0,0,0,0}, o2 = {0,0,0,0}, o3 = {0,0,0,0};
    f32x4 lacc = {0.f, 0.f, 0.f, 0.f};
    float mr0 = -1e30f, mr1 = -1e30f, mr2 = -1e30f, mr3 = -1e30f;

    const unsigned char* adjrow =
        adjp + (size_t)(b * 512 + (wi0 >> 2) + quad) * (S_ * 4);
    const float* maskrow = mask + (size_t)b * S_;
    const f16* vtb = vt + (size_t)bn * DH * S_;

// one biaffine term r: z = Q'_r K^T, gated by adjacency bit r
#define Z_ACC(R, QPa, QPb) {                                                 \
    f32x4 z_ = {0.f, 0.f, 0.f, 0.f};                                         \
    z_ = MFMA16(QPa, bk0_, z_);                                              \
    z_ = MFMA16(QPb, bk1_, z_);                                              \
    t0_ = fmaf((float)((c0_ >> (R)) & 1u), z_[0], t0_);                      \
    t1_ = fmaf((float)((c1_ >> (R)) & 1u), z_[1], t1_);                      \
    t2_ = fmaf((float)((c2_ >> (R)) & 1u), z_[2], t2_);                      \
    t3_ = fmaf((float)((c3_ >> (R)) & 1u), z_[3], t3_);                      \
}

// scores for one 16-col group -> 4 named outputs
#define SCORE1(JCOL, O0, O1, O2, O3) do {                                    \
    const int jcol_ = (JCOL);                                                \
    const f16* kp_ = k + kbase + (size_t)jcol_ * DH + quad * 8;              \
    f16x8 bk0_ = *(const f16x8*)(kp_);                                       \
    f16x8 bk1_ = *(const f16x8*)(kp_ + 32);                                  \
    f32x4 aqk_ = {0.f, 0.f, 0.f, 0.f};                                       \
    aqk_ = MFMA16(aq0, bk0_, aqk_);                                          \
    aqk_ = MFMA16(aq1, bk1_, aqk_);                                          \
    uchar4 a4_ = *(const uchar4*)(adjrow + (size_t)jcol_ * 4);               \
    unsigned int c0_ = a4_.x, c1_ = a4_.y, c2_ = a4_.z, c3_ = a4_.w;         \
    float mkL_ = maskrow[jcol_] * L2E;                                       \
    float t0_ = aqk_[0], t1_ = aqk_[1], t2_ = aqk_[2], t3_ = aqk_[3];        \
    Z_ACC(0, qp0a, qp0b)                                                     \
    Z_ACC(1, qp1a, qp1b)                                                     \
    Z_ACC(2, qp2a, qp2b)                                                     \
    Z_ACC(3, qp3a, qp3b)                                                     \
    Z_ACC(4, qp4a, qp4b)                                                     \
    O0 = fmaf(t0_, SCL, lut[c0_] + mkL_);                                    \
    O1 = fmaf(t1_, SCL, lut[c1_] + mkL_);                                    \
    O2 = fmaf(t2_, SCL, lut[c2_] + mkL_);                                    \
    O3 = fmaf(t3_, SCL, lut[c3_] + mkL_);                                    \
} while (0)

#define SCORES(T, P) do {                                                    \
    SCORE1((T) * 64 +  0 + l15, P##_0,  P##_1,  P##_2,  P##_3);              \
    SCORE1((T) * 64 + 16 + l15, P##_4,  P##_5,  P##_6,  P##_7);              \
    SCORE1((T) * 64 + 32 + l15, P##_8,  P##_9,  P##_10, P##_11);             \
    SCORE1((T) * 64 + 48 + l15, P##_12, P##_13, P##_14, P##_15);             \
} while (0)

// online softmax + P pack + rescale + PV for tile T (all-named state)
#define SMPV(T, P) do {                                                      \
    const int j0_ = (T) * 64;                                                \
    float nm0_ = fmaxf(fmaxf(P##_0,  P##_4),  fmaxf(P##_8,  P##_12));        \
    float nm1_ = fmaxf(fmaxf(P##_1,  P##_5),  fmaxf(P##_9,  P##_13));        \
    float nm2_ = fmaxf(fmaxf(P##_2,  P##_6),  fmaxf(P##_10, P##_14));        \
    float nm3_ = fmaxf(fmaxf(P##_3,  P##_7),  fmaxf(P##_11, P##_15));        \
    _Pragma("unroll")                                                        \
    for (int off = 1; off < 16; off <<= 1) {                                 \
        nm0_ = fmaxf(nm0_, __shfl_xor(nm0_, off));                           \
        nm1_ = fmaxf(nm1_, __shfl_xor(nm1_, off));                           \
        nm2_ = fmaxf(nm2_, __shfl_xor(nm2_, off));                           \
        nm3_ = fmaxf(nm3_, __shfl_xor(nm3_, off));                           \
    }                                                                        \
    nm0_ = fmaxf(mr0, nm0_); float al0_ = exp2fast(mr0 - nm0_); mr0 = nm0_;  \
    nm1_ = fmaxf(mr1, nm1_); float al1_ = exp2fast(mr1 - nm1_); mr1 = nm1_;  \
    nm2_ = fmaxf(mr2, nm2_); float al2_ = exp2fast(mr2 - nm2_); mr2 = nm2_;  \
    nm3_ = fmaxf(mr3, nm3_); float al3_ = exp2fast(mr3 - nm3_); mr3 = nm3_;  \
    Pw[(quad * 4 + 0) * 72 +  0 + l15] = (f16)exp2fast(P##_0  - mr0);        \
    Pw[(quad * 4 + 1) * 72 +  0 + l15] = (f16)exp2fast(P##_1  - mr1);        \
    Pw[(quad * 4 + 2) * 72 +  0 + l15] = (f16)exp2fast(P##_2  - mr2);        \
    Pw[(quad * 4 + 3) * 72 +  0 + l15] = (f16)exp2fast(P##_3  - mr3);        \
    Pw[(quad * 4 + 0) * 72 + 16 + l15] = (f16)exp2fast(P##_4  - mr0);        \
    Pw[(quad * 4 + 1) * 72 + 16 + l15] = (f16)exp2fast(P##_5  - mr1);        \
    Pw[(quad * 4 + 2) * 72 + 16 + l15] = (f16)exp2fast(P##_6  - mr2);        \
    Pw[(quad * 4 + 3) * 72 + 16 + l15] = (f16)exp2fast(P##_7  - mr3);        \
    Pw[(quad * 4 + 0) * 72 + 32 + l15] = (f16)exp2fast(P##_8  - mr0);        \
    Pw[(quad * 4 + 1) * 72 + 32 + l15] = (f16)exp2fast(P##_9  - mr1);        \
    Pw[(quad * 4 + 2) * 72 + 32 + l15] = (f16)exp2fast(P##_10 - mr2);        \
    Pw[(quad * 4 + 3) * 72 + 32 + l15] = (f16)exp2fast(P##_11 - mr3);        \
    Pw[(quad * 4 + 0) * 72 + 48 + l15] = (f16)exp2fast(P##_12 - mr0);        \
    Pw[(quad * 4 + 1) * 72 + 48 + l15] = (f16)exp2fast(P##_13 - mr1);        \
    Pw[(quad * 4 + 2) * 72 + 48 + l15] = (f16)exp2fast(P##_14 - mr2);        \
    Pw[(quad * 4 + 3) * 72 + 48 + l15] = (f16)exp2fast(P##_15 - mr3);        \
    lacc[0] *= al0_; lacc[1] *= al1_; lacc[2] *= al2_; lacc[3] *= al3_;      \
    o0[0] *= al0_; o0[1] *= al1_; o0[2] *= al2_; o0[3] *= al3_;              \
    o1[0] *= al0_; o1[1] *= al1_; o1[2] *= al2_; o1[3] *= al3_;              \
    o2[0] *= al0_; o2[1] *= al1_; o2[2] *= al2_; o2[3] *= al3_;              \
    o3[0] *= al0_; o3[1] *= al1_; o3[2] *= al2_; o3[3] *= al3_;              \
    f16x8 pa0_ = *(const f16x8*)&Pw[l15 * 72 + quad * 8];                    \
    f16x8 pa1_ = *(const f16x8*)&Pw[l15 * 72 + quad * 8 + 32];               \
    lacc = MFMA16(pa0_, ones, lacc);                                         \
    lacc = MFMA16(pa1_, ones, lacc);                                         \
    { const f16* vp_ = vtb + (size_t)( 0 + l15) * S_ + j0_ + quad * 8;       \
      o0 = MFMA16(pa0_, *(const f16x8*)(vp_), o0);                           \
      o0 = MFMA16(pa1_, *(const f16x8*)(vp_ + 32), o0); }                    \
    { const f16* vp_ = vtb + (size_t)(16 + l15) * S_ + j0_ + quad * 8;       \
      o1 = MFMA16(pa0_, *(const f16x8*)(vp_), o1);                           \
      o1 = MFMA16(pa1_, *(const f16x8*)(vp_ + 32), o1); }                    \
    { const f16* vp_ = vtb + (size_t)(32 + l15) * S_ + j0_ + quad * 8;       \
      o2 = MFMA16(pa0_, *(const f16x8*)(vp_), o2);                           \
      o2 = MFMA16(pa1_, *(const f16x8*)(vp_ + 32), o2); }                    \
    { const f16* vp_ = vtb + (size_t)(48 + l15) * S_ + j0_ + quad * 8;       \
      o3 = MFMA16(pa0_, *(const f16x8*)(vp_), o3);                           \
      o3 = MFMA16(pa1_, *(const f16x8*)(vp_ + 32), o3); }                    \
} while (0)

    // 32 individually-named score scalars (no arrays -> no scratch)
    float sA_0, sA_1, sA_2, sA_3, sA_4, sA_5, sA_6, sA_7,
          sA_8, sA_9, sA_10, sA_11, sA_12, sA_13, sA_14, sA_15;
    float sB_0, sB_1, sB_2, sB_3, sB_4, sB_5, sB_6, sB_7,
          sB_8, sB_9, sB_10, sB_11, sB_12, sB_13, sB_14, sB_15;

    SCORES(0, sA);
#pragma unroll 1
    for (int tt = 0; tt < 16; ++tt) {
        SCORES(2 * tt + 1, sB);      // independent of SMPV(sA) -> overlap
        SMPV(2 * tt, sA);
        if (tt < 15) SCORES(2 * tt + 2, sA);
        SMPV(2 * tt + 1, sB);
    }

#undef SCORES
#undef SCORE1
#undef Z_ACC
#undef SMPV

    // ---- epilogue ----
    {
        float inv0 = 1.f / lacc[0];
        float inv1 = 1.f / lacc[1];
        float inv2 = 1.f / lacc[2];
        float inv3 = 1.f / lacc[3];
        const size_t ob = ((size_t)b * S_ + (wi0 + quad * 4)) * H_ + n * DH + l15;
        out[ob + 0 * H_ +  0] = o0[0] * inv0;
        out[ob + 0 * H_ + 16] = o1[0] * inv0;
        out[ob + 0 * H_ + 32] = o2[0] * inv0;
        out[ob + 0 * H_ + 48] = o3[0] * inv0;
        out[ob + 1 * H_ +  0] = o0[1] * inv1;
        out[ob + 1 * H_ + 16] = o1[1] * inv1;
        out[ob + 1 * H_ + 32] = o2[1] * inv1;
        out[ob + 1 * H_ + 48] = o3[1] * inv1;
        out[ob + 2 * H_ +  0] = o0[2] * inv2;
        out[ob + 2 * H_ + 16] = o1[2] * inv2;
        out[ob + 2 * H_ + 32] = o2[2] * inv2;
        out[ob + 2 * H_ + 48] = o3[2] * inv2;
        out[ob + 3 * H_ +  0] = o0[3] * inv3;
        out[ob + 3 * H_ + 16] = o1[3] * inv3;
        out[ob + 3 * H_ + 32] = o2[3] * inv3;
        out[ob + 3 * H_ + 48] = o3[3] * inv3;
    }
}

// ---------------------------------------------------------------------------
extern "C" void kernel_launch(void* const* d_in, const int* in_sizes, int n_in,
                              void* d_out, int out_size, void* d_ws, size_t ws_size,
                              hipStream_t stream)
{
    const float* hs   = (const float*)d_in[0];
    const float* mask = (const float*)d_in[1];
    const float* adj  = (const float*)d_in[2];
    const float* Wq   = (const float*)d_in[3];
    const float* bq   = (const float*)d_in[4];
    const float* Wk   = (const float*)d_in[5];
    const float* bk   = (const float*)d_in[6];
    const float* Wv   = (const float*)d_in[7];
    const float* bv   = (const float*)d_in[8];
    const float* bili = (const float*)d_in[9];
    const float* absb = (const float*)d_in[10];
    float* out = (float*)d_out;

    const size_t QKV = (size_t)BN * S_ * DH;       // 3.1M elems
    f16* q  = (f16*)d_ws;
    f16* k  = q + QKV;
    f16* vt = k + QKV;
    unsigned char* adjp = (unsigned char*)(vt + QKV);       // 8 MB
    f16* xh = (f16*)(adjp + (size_t)B_ * 512 * S_ * 4);
    f16* wh = xh + (size_t)B_ * S_ * H_;                    // Wq|Wk|Wv f16

    const int total4 = NX4 + 3 * NW4;
    cvtall<<<(total4 + 255) / 256, 256, 0, stream>>>(hs, Wq, Wk, Wv, xh, wh);
    qkv_gemm<<<dim3(12, 64), 256, 0, stream>>>(xh, wh, bq, bk, bv, q, k, vt);
    adjpack<<<2048, 256, 0, stream>>>(adj, adjp);
    attn<<<768, 256, 0, stream>>>(q, k, vt, bili, adjp, mask, absb, out);
}

// Round 7
// 506.247 us; speedup vs baseline: 1.8226x; 1.8168x over previous
//
#include <hip/hip_runtime.h>
#include <cstdint>
#include <cstddef>

#define B_  2
#define S_  2048
#define H_  768
#define NH  12
#define DH  64
#define RD  5
#define BN  (B_*NH)   // 24

typedef _Float16 f16;
typedef __attribute__((ext_vector_type(8))) _Float16 f16x8;
typedef __attribute__((ext_vector_type(4))) float f32x4;

#define MFMA16(a, b, c) __builtin_amdgcn_mfma_f32_16x16x32_f16((a), (b), (c), 0, 0, 0)

#if __has_builtin(__builtin_amdgcn_exp2f)
__device__ __forceinline__ float exp2fast(float x) { return __builtin_amdgcn_exp2f(x); }
#else
__device__ __forceinline__ float exp2fast(float x) { return __expf(0.69314718056f * x); }
#endif

#define SCL 0.1803368801f   /* 0.125 * log2(e) */
#define L2E 1.44269504f

#define NX4 ((B_*S_*H_)/4)   // 786432
#define NW4 ((H_*H_)/4)      // 147456

// ---------------------------------------------------------------------------
// Kernel 0: fused fp32 -> fp16 conversion of x, Wq, Wk, Wv (one launch).
// ---------------------------------------------------------------------------
__global__ __launch_bounds__(256) void cvtall(
    const float* __restrict__ x,
    const float* __restrict__ wq, const float* __restrict__ wk,
    const float* __restrict__ wv,
    f16* __restrict__ xh, f16* __restrict__ wh)
{
    int idx = blockIdx.x * 256 + threadIdx.x;
    const int total4 = NX4 + 3 * NW4;
    if (idx >= total4) return;
    const float* src;
    f16* dst;
    int off;
    if (idx < NX4) {
        src = x; dst = xh; off = idx;
    } else {
        int r = idx - NX4;
        int which = r / NW4;
        off = r - which * NW4;
        src = (which == 0) ? wq : (which == 1) ? wk : wv;
        dst = wh + (size_t)which * H_ * H_;
    }
    float4 f = ((const float4*)src)[off];
    f16 h[4] = {(f16)f.x, (f16)f.y, (f16)f.z, (f16)f.w};
    ((ushort4*)dst)[off] = *(const ushort4*)h;
}

// ---------------------------------------------------------------------------
// Kernel 1: MFMA QKV projection (fp16 in/out).  One block: 64 rows x 64 cols
// of q,k,v (same x tile, three W tiles).  V written transposed vt[bn][d][s].
// grid (12, 64).
// ---------------------------------------------------------------------------
__global__ __launch_bounds__(256, 3) void qkv_gemm(
    const f16* __restrict__ xh, const f16* __restrict__ wh,
    const float* __restrict__ bq, const float* __restrict__ bk,
    const float* __restrict__ bv,
    f16* __restrict__ qo, f16* __restrict__ ko, f16* __restrict__ vt)
{
    __shared__ __align__(16) f16 Xs[64][72];
    __shared__ __align__(16) f16 Ws[3][64][72];

    const int tid = threadIdx.x;
    const int n  = blockIdx.x;          // head / 64-col tile
    const int m0 = blockIdx.y * 64;
    const int w = tid >> 6, lane = tid & 63;
    const int l15 = lane & 15, quad = lane >> 4;
    const int srow = tid >> 2, sc0 = (tid & 3) * 16;

    f32x4 acc[3][4];
#pragma unroll
    for (int i = 0; i < 3; ++i)
#pragma unroll
        for (int ns = 0; ns < 4; ++ns) acc[i][ns] = (f32x4){0.f, 0.f, 0.f, 0.f};

    const f16* xsrc = xh + (size_t)(m0 + srow) * H_ + sc0;
    const f16* wsrc = wh + (size_t)(n * 64 + srow) * H_ + sc0;

    for (int kc = 0; kc < 12; ++kc) {
        __syncthreads();
        {
            const f16* s0 = xsrc + kc * 64;
            *(f16x8*)&Xs[srow][sc0]     = *(const f16x8*)(s0);
            *(f16x8*)&Xs[srow][sc0 + 8] = *(const f16x8*)(s0 + 8);
        }
#pragma unroll
        for (int i = 0; i < 3; ++i) {
            const f16* s0 = wsrc + (size_t)i * H_ * H_ + kc * 64;
            *(f16x8*)&Ws[i][srow][sc0]     = *(const f16x8*)(s0);
            *(f16x8*)&Ws[i][srow][sc0 + 8] = *(const f16x8*)(s0 + 8);
        }
        __syncthreads();

        f16x8 a0 = *(const f16x8*)&Xs[w * 16 + l15][quad * 8];
        f16x8 a1 = *(const f16x8*)&Xs[w * 16 + l15][quad * 8 + 32];
#pragma unroll
        for (int i = 0; i < 3; ++i)
#pragma unroll
            for (int ns = 0; ns < 4; ++ns) {
                f16x8 b0 = *(const f16x8*)&Ws[i][ns * 16 + l15][quad * 8];
                f16x8 b1 = *(const f16x8*)&Ws[i][ns * 16 + l15][quad * 8 + 32];
                acc[i][ns] = MFMA16(a0, b0, acc[i][ns]);
                acc[i][ns] = MFMA16(a1, b1, acc[i][ns]);
            }
    }
    __syncthreads();

    const float* bias[3] = {bq, bk, bv};
    f16 (*T0)[72] = Xs;      // q
    f16 (*T1)[72] = Ws[0];   // k
    f16 (*T2)[72] = Ws[1];   // v
#pragma unroll
    for (int i = 0; i < 3; ++i) {
        f16 (*T)[72] = (i == 0) ? T0 : (i == 1) ? T1 : T2;
#pragma unroll
        for (int ns = 0; ns < 4; ++ns) {
            float bb = bias[i][n * 64 + ns * 16 + l15];
#pragma unroll
            for (int reg = 0; reg < 4; ++reg)
                T[w * 16 + quad * 4 + reg][ns * 16 + l15] =
                    (f16)(acc[i][ns][reg] + bb);
        }
    }
    __syncthreads();

    const int mrow = m0 + srow;
    const int bb2 = mrow >> 11, ss = mrow & 2047;
    {
        f16* dst = qo + ((size_t)(bb2 * NH + n) * S_ + ss) * DH + sc0;
        *(f16x8*)dst       = *(const f16x8*)&T0[srow][sc0];
        *(f16x8*)(dst + 8) = *(const f16x8*)&T0[srow][sc0 + 8];
    }
    {
        f16* dst = ko + ((size_t)(bb2 * NH + n) * S_ + ss) * DH + sc0;
        *(f16x8*)dst       = *(const f16x8*)&T1[srow][sc0];
        *(f16x8*)(dst + 8) = *(const f16x8*)&T1[srow][sc0 + 8];
    }
    {
        f16 tmp[16];
#pragma unroll
        for (int u = 0; u < 16; ++u) tmp[u] = T2[sc0 + u][srow];
        f16* dst = vt + ((size_t)(bb2 * NH + n) * DH + srow) * S_ + (m0 & 2047) + sc0;
        *(f16x8*)dst       = *(const f16x8*)&tmp[0];
        *(f16x8*)(dst + 8) = *(const f16x8*)&tmp[8];
    }
}

// ---------------------------------------------------------------------------
// Kernel 2: pack binary adjacency -> bytes, i-quad interleaved, VECTORIZED.
// ---------------------------------------------------------------------------
__global__ __launch_bounds__(256) void adjpack(
    const float* __restrict__ adj, unsigned char* __restrict__ adjp)
{
    const int idx4 = blockIdx.x * 256 + threadIdx.x;   // [0, 2^19)
    const int j4 = idx4 & 511;          // j = j4*4
    const int iq = (idx4 >> 9) & 511;
    const int b  = idx4 >> 18;
    unsigned int wbits[4] = {0, 0, 0, 0};   // per-j packed (ii in byte lanes)
#pragma unroll
    for (int r = 0; r < RD; ++r) {
#pragma unroll
        for (int ii = 0; ii < 4; ++ii) {
            float4 v = *(const float4*)(adj +
                (((size_t)(r * B_ + b) * S_) + iq * 4 + ii) * S_ + j4 * 4);
            float vv[4] = {v.x, v.y, v.z, v.w};
#pragma unroll
            for (int jj = 0; jj < 4; ++jj)
                wbits[jj] |= (vv[jj] != 0.f ? 1u : 0u) << (r + 8 * ii);
        }
    }
    uint4 pk = {wbits[0], wbits[1], wbits[2], wbits[3]};
    *(uint4*)(adjp + ((size_t)(b * 512 + iq) * S_ + j4 * 4) * 4) = pk;
}

// ---------------------------------------------------------------------------
// Kernel 3: MFMA flash attention = round-3 verified structure (VGPR-lean,
// no scratch, 224 us) + SINGLE-SET K/V register prefetch:
//   - kb (8 x f16x8): K frags for tile t, loaded at end of tile t-1 ->
//     K latency hides under softmax+PV of t-1 (WAR overwrite, no dbuf).
//   - vb (8 x f16x8): V frags for tile t, loaded at tile top ->
//     V latency hides under the 48 SCORES MFMAs.
// Rounds 4/5 proved DOUBLE-buffered scores (~190+ unified regs) spill;
// this single-set scheme peaks ~160 < the (256,3) budget (~170).
// Occupancy stays grid-pinned at 3 waves/SIMD; the target is the per-wave
// load->use serial chains that dominate the 80% stall fraction.
// (Resubmitted unchanged: round-6 bench failed on container infra, no data.)
// ---------------------------------------------------------------------------
__global__ __launch_bounds__(256, 3) void attn(
    const f16* __restrict__ q, const f16* __restrict__ k, const f16* __restrict__ vt,
    const float* __restrict__ bili, const unsigned char* __restrict__ adjp,
    const float* __restrict__ mask, const float* __restrict__ absb,
    float* __restrict__ out)
{
    __shared__ __align__(16) char smem[9216 + 9216 + 128];
    f16*   Mt  = (f16*)smem;                    // [64][72] (prologue only)
    f16*   Pb  = (f16*)(smem + 9216);           // [4][16][72]
    float* lut = (float*)(smem + 9216 + 9216);  // [32]

    const int tid = threadIdx.x;
    const int idx = blockIdx.x;
    const int g = idx & 7;
    const int it = (idx >> 3) & 31;
    const int bn = 8 * (idx >> 8) + g;
    const int b = bn / NH, n = bn % NH;
    const int w = tid >> 6, lane = tid & 63;
    const int l15 = lane & 15, quad = lane >> 4;
    const int wi0 = it * 64 + w * 16;
    const size_t kbase = (size_t)bn * S_ * DH;

    if (tid < 32) {
        float a = 0.f;
#pragma unroll
        for (int r = 0; r < RD; ++r)
            if (tid & (1 << r)) a += absb[r * NH + n];
        lut[tid] = a * SCL;
    }

    const f16* qrow = q + kbase + (size_t)(wi0 + l15) * DH + quad * 8;
    f16x8 aq0 = *(const f16x8*)(qrow);
    f16x8 aq1 = *(const f16x8*)(qrow + 32);

    f16* Pw = Pb + w * 16 * 72;

    // ---- build Q'_r A-frags via MFMA (round-3 verified prologue) ----
    f16x8 aqp[RD][2];
#pragma unroll
    for (int r = 0; r < RD; ++r) {
        __syncthreads();
        {
            int p = tid >> 2, q0 = (tid & 3) * 16;
            const float* src = bili + ((size_t)(r * NH + n) * DH + p) * DH + q0;
            float4 g0 = ((const float4*)src)[0];
            float4 g1 = ((const float4*)src)[1];
            float4 g2 = ((const float4*)src)[2];
            float4 g3 = ((const float4*)src)[3];
            float mv[16] = {g0.x, g0.y, g0.z, g0.w, g1.x, g1.y, g1.z, g1.w,
                            g2.x, g2.y, g2.z, g2.w, g3.x, g3.y, g3.z, g3.w};
#pragma unroll
            for (int u = 0; u < 16; ++u) Mt[(q0 + u) * 72 + p] = (f16)mv[u];
        }
        __syncthreads();
#pragma unroll
        for (int ns = 0; ns < 4; ++ns) {
            f16x8 b0 = *(const f16x8*)&Mt[(ns * 16 + l15) * 72 + quad * 8];
            f16x8 b1 = *(const f16x8*)&Mt[(ns * 16 + l15) * 72 + quad * 8 + 32];
            f32x4 d = {0.f, 0.f, 0.f, 0.f};
            d = MFMA16(aq0, b0, d);
            d = MFMA16(aq1, b1, d);
#pragma unroll
            for (int reg = 0; reg < 4; ++reg)
                Pw[(quad * 4 + reg) * 72 + ns * 16 + l15] = (f16)d[reg];
        }
        aqp[r][0] = *(const f16x8*)&Pw[l15 * 72 + quad * 8];
        aqp[r][1] = *(const f16x8*)&Pw[l15 * 72 + quad * 8 + 32];
    }

    f16x8 ones;
#pragma unroll
    for (int u = 0; u < 8; ++u) ones[u] = (f16)1.0f;

    f32x4 o[4] = {{0,0,0,0},{0,0,0,0},{0,0,0,0},{0,0,0,0}};
    f32x4 lacc = {0.f, 0.f, 0.f, 0.f};
    float mrun[4] = {-1e30f, -1e30f, -1e30f, -1e30f};

    const unsigned char* adjrow =
        adjp + (size_t)(b * 512 + (wi0 >> 2) + quad) * (S_ * 4);
    const float* maskrow = mask + (size_t)b * S_;
    const f16* vtb = vt + (size_t)bn * DH * S_;

    // ---- named K/V fragment sets (single-set prefetch, WAR overwrite) ----
    f16x8 kb0a, kb0b, kb1a, kb1b, kb2a, kb2b, kb3a, kb3b;
    f16x8 vb0a, vb0b, vb1a, vb1b, vb2a, vb2b, vb3a, vb3b;

#define LOAD_KB(T) do {                                                      \
    const f16* kp_ = k + kbase + (size_t)((T) * 64 + l15) * DH + quad * 8;   \
    kb0a = *(const f16x8*)(kp_);                                             \
    kb0b = *(const f16x8*)(kp_ + 32);                                        \
    kb1a = *(const f16x8*)(kp_ + 16 * DH);                                   \
    kb1b = *(const f16x8*)(kp_ + 16 * DH + 32);                              \
    kb2a = *(const f16x8*)(kp_ + 32 * DH);                                   \
    kb2b = *(const f16x8*)(kp_ + 32 * DH + 32);                              \
    kb3a = *(const f16x8*)(kp_ + 48 * DH);                                   \
    kb3b = *(const f16x8*)(kp_ + 48 * DH + 32);                              \
} while (0)

#define LOAD_VB(T) do {                                                      \
    const f16* vp_ = vtb + (size_t)l15 * S_ + (T) * 64 + quad * 8;           \
    vb0a = *(const f16x8*)(vp_);                                             \
    vb0b = *(const f16x8*)(vp_ + 32);                                        \
    vb1a = *(const f16x8*)(vp_ + 16 * S_);                                   \
    vb1b = *(const f16x8*)(vp_ + 16 * S_ + 32);                              \
    vb2a = *(const f16x8*)(vp_ + 32 * S_);                                   \
    vb2b = *(const f16x8*)(vp_ + 32 * S_ + 32);                              \
    vb3a = *(const f16x8*)(vp_ + 48 * S_);                                   \
    vb3b = *(const f16x8*)(vp_ + 48 * S_ + 32);                              \
} while (0)

// scores for one 16-col group from pre-loaded K frags (round-3 math)
#define SCORE1(T, JS, KA, KB_, O0, O1, O2, O3) do {                          \
    const int jcol_ = (T) * 64 + (JS) * 16 + l15;                            \
    f32x4 aqk_ = {0.f, 0.f, 0.f, 0.f};                                       \
    aqk_ = MFMA16(aq0, KA, aqk_);                                            \
    aqk_ = MFMA16(aq1, KB_, aqk_);                                           \
    uchar4 a4_ = *(const uchar4*)(adjrow + (size_t)jcol_ * 4);               \
    unsigned int c0_ = a4_.x, c1_ = a4_.y, c2_ = a4_.z, c3_ = a4_.w;         \
    float mkL_ = maskrow[jcol_] * L2E;                                       \
    float t0_ = aqk_[0], t1_ = aqk_[1], t2_ = aqk_[2], t3_ = aqk_[3];        \
    _Pragma("unroll")                                                        \
    for (int r = 0; r < RD; ++r) {                                           \
        f32x4 z_ = {0.f, 0.f, 0.f, 0.f};                                     \
        z_ = MFMA16(aqp[r][0], KA, z_);                                      \
        z_ = MFMA16(aqp[r][1], KB_, z_);                                     \
        t0_ = fmaf((float)((c0_ >> r) & 1u), z_[0], t0_);                    \
        t1_ = fmaf((float)((c1_ >> r) & 1u), z_[1], t1_);                    \
        t2_ = fmaf((float)((c2_ >> r) & 1u), z_[2], t2_);                    \
        t3_ = fmaf((float)((c3_ >> r) & 1u), z_[3], t3_);                    \
    }                                                                        \
    O0 = fmaf(t0_, SCL, lut[c0_] + mkL_);                                    \
    O1 = fmaf(t1_, SCL, lut[c1_] + mkL_);                                    \
    O2 = fmaf(t2_, SCL, lut[c2_] + mkL_);                                    \
    O3 = fmaf(t3_, SCL, lut[c3_] + mkL_);                                    \
} while (0)

    LOAD_KB(0);

#pragma unroll 1
    for (int t = 0; t < 32; ++t) {
        const int j0 = t * 64;

        // V frags for THIS tile: latency hides under the 48 SCORES MFMAs
        LOAD_VB(t);

        float sc[4][4];
        SCORE1(t, 0, kb0a, kb0b, sc[0][0], sc[0][1], sc[0][2], sc[0][3]);
        SCORE1(t, 1, kb1a, kb1b, sc[1][0], sc[1][1], sc[1][2], sc[1][3]);
        SCORE1(t, 2, kb2a, kb2b, sc[2][0], sc[2][1], sc[2][2], sc[2][3]);
        SCORE1(t, 3, kb3a, kb3b, sc[3][0], sc[3][1], sc[3][2], sc[3][3]);

        // K frags for NEXT tile: kb dead after SCORES; latency hides under
        // softmax + PV.  Last iteration clamps (harmless re-load of t=31).
        {
            int tn = t + 1;
            if (tn > 31) tn = 31;
            LOAD_KB(tn);
        }

        // ---- online softmax (exp2 domain; rows in 16-lane groups) ----
        float alpha[4];
#pragma unroll
        for (int reg = 0; reg < 4; ++reg) {
            float nm = fmaxf(fmaxf(sc[0][reg], sc[1][reg]),
                             fmaxf(sc[2][reg], sc[3][reg]));
#pragma unroll
            for (int off = 1; off < 16; off <<= 1)
                nm = fmaxf(nm, __shfl_xor(nm, off));
            float mn = fmaxf(mrun[reg], nm);
            alpha[reg] = exp2fast(mrun[reg] - mn);
            mrun[reg] = mn;
        }
#pragma unroll
        for (int js = 0; js < 4; ++js)
#pragma unroll
            for (int reg = 0; reg < 4; ++reg) {
                float p = exp2fast(sc[js][reg] - mrun[reg]);
                Pw[(quad * 4 + reg) * 72 + js * 16 + l15] = (f16)p;
            }
#pragma unroll
        for (int reg = 0; reg < 4; ++reg) {
            lacc[reg] *= alpha[reg];
#pragma unroll
            for (int ds = 0; ds < 4; ++ds) o[ds][reg] *= alpha[reg];
        }

        // ---- PV + row-sum via MFMA (V already in registers) ----
        f16x8 pa0 = *(const f16x8*)&Pw[l15 * 72 + quad * 8];
        f16x8 pa1 = *(const f16x8*)&Pw[l15 * 72 + quad * 8 + 32];
        lacc = MFMA16(pa0, ones, lacc);
        lacc = MFMA16(pa1, ones, lacc);
        o[0] = MFMA16(pa0, vb0a, o[0]);
        o[0] = MFMA16(pa1, vb0b, o[0]);
        o[1] = MFMA16(pa0, vb1a, o[1]);
        o[1] = MFMA16(pa1, vb1b, o[1]);
        o[2] = MFMA16(pa0, vb2a, o[2]);
        o[2] = MFMA16(pa1, vb2b, o[2]);
        o[3] = MFMA16(pa0, vb3a, o[3]);
        o[3] = MFMA16(pa1, vb3b, o[3]);
    }

#undef SCORE1
#undef LOAD_KB
#undef LOAD_VB

    // ---- epilogue ----
#pragma unroll
    for (int reg = 0; reg < 4; ++reg) {
        float inv = 1.f / lacc[reg];
        int i = wi0 + quad * 4 + reg;
#pragma unroll
        for (int ds = 0; ds < 4; ++ds)
            out[((size_t)b * S_ + i) * H_ + n * DH + ds * 16 + l15] =
                o[ds][reg] * inv;
    }
}

// ---------------------------------------------------------------------------
extern "C" void kernel_launch(void* const* d_in, const int* in_sizes, int n_in,
                              void* d_out, int out_size, void* d_ws, size_t ws_size,
                              hipStream_t stream)
{
    const float* hs   = (const float*)d_in[0];
    const float* mask = (const float*)d_in[1];
    const float* adj  = (const float*)d_in[2];
    const float* Wq   = (const float*)d_in[3];
    const float* bq   = (const float*)d_in[4];
    const float* Wk   = (const float*)d_in[5];
    const float* bk   = (const float*)d_in[6];
    const float* Wv   = (const float*)d_in[7];
    const float* bv   = (const float*)d_in[8];
    const float* bili = (const float*)d_in[9];
    const float* absb = (const float*)d_in[10];
    float* out = (float*)d_out;

    const size_t QKV = (size_t)BN * S_ * DH;       // 3.1M elems
    f16* q  = (f16*)d_ws;
    f16* k  = q + QKV;
    f16* vt = k + QKV;
    unsigned char* adjp = (unsigned char*)(vt + QKV);       // 8 MB
    f16* xh = (f16*)(adjp + (size_t)B_ * 512 * S_ * 4);
    f16* wh = xh + (size_t)B_ * S_ * H_;                    // Wq|Wk|Wv f16

    const int total4 = NX4 + 3 * NW4;
    cvtall<<<(total4 + 255) / 256, 256, 0, stream>>>(hs, Wq, Wk, Wv, xh, wh);
    qkv_gemm<<<dim3(12, 64), 256, 0, stream>>>(xh, wh, bq, bk, bv, q, k, vt);
    adjpack<<<2048, 256, 0, stream>>>(adj, adjp);
    attn<<<768, 256, 0, stream>>>(q, k, vt, bili, adjp, mask, absb, out);
}